// Round 1
// baseline (1244.952 us; speedup 1.0000x reference)
//
#include <hip/hip_runtime.h>
#include <cstdint>
#include <cstddef>

// Problem constants (match reference)
#define Bn   2
#define Wn   8
#define Nn   10000
#define Fin  5
#define En   80000
#define Hn   128
#define BWn  (Bn*Wn)        // 16
#define ROWS (BWn*Nn)       // 160000
#define MR   (Bn*Nn)        // 20000  (LSTM batch rows)

// ---------------- CSR build ----------------

__global__ void init_counts_kernel(int* counts) {
    int i = blockIdx.x * blockDim.x + threadIdx.x;
    if (i < Nn) counts[i] = 1;   // self-loop contributes 1 to every dst
}

__global__ void count_edges_kernel(const int* __restrict__ ei, int* counts) {
    int e = blockIdx.x * blockDim.x + threadIdx.x;
    if (e < En) atomicAdd(&counts[ei[En + e]], 1);   // dst row
}

enum { CHUNK = 10 };  // ceil(10000/1024)
static_assert(CHUNK * 1024 >= Nn, "scan chunk");

__global__ __launch_bounds__(1024) void scan_kernel(
    const int* __restrict__ counts, int* __restrict__ row_ptr,
    int* __restrict__ fill_ptr, float* __restrict__ dinv) {
    __shared__ int sums[1024];
    const int t = threadIdx.x;
    const int base = t * CHUNK;
    int cnt[CHUNK];
    int s = 0;
    #pragma unroll
    for (int i = 0; i < CHUNK; ++i) {
        int idx = base + i;
        int v = (idx < Nn) ? counts[idx] : 0;
        cnt[i] = v; s += v;
    }
    sums[t] = s;
    __syncthreads();
    for (int off = 1; off < 1024; off <<= 1) {
        int v = (t >= off) ? sums[t - off] : 0;
        __syncthreads();
        sums[t] += v;
        __syncthreads();
    }
    int excl = (t == 0) ? 0 : sums[t - 1];
    #pragma unroll
    for (int i = 0; i < CHUNK; ++i) {
        int idx = base + i;
        if (idx < Nn) {
            row_ptr[idx] = excl;
            fill_ptr[idx] = excl;
            dinv[idx] = rsqrtf((float)cnt[i]);
            excl += cnt[i];
        }
    }
    if (t == 1023) row_ptr[Nn] = excl;   // = E + N
}

__global__ void fill_kernel(const int* __restrict__ ei,
                            const float* __restrict__ dinv,
                            int* fill_ptr, int* __restrict__ col,
                            float* __restrict__ wgt) {
    int i = blockIdx.x * blockDim.x + threadIdx.x;
    if (i < Nn) {
        // self loop
        int p = atomicAdd(&fill_ptr[i], 1);
        col[p] = i;
        wgt[p] = dinv[i] * dinv[i];
    } else if (i < Nn + En) {
        int e = i - Nn;
        int s = ei[e];
        int d = ei[En + e];
        int p = atomicAdd(&fill_ptr[d], 1);
        col[p] = s;
        wgt[p] = dinv[s] * dinv[d];
    }
}

// ---------------- small helpers ----------------

__global__ void bsum_kernel(const float* __restrict__ a, const float* __restrict__ b,
                            float* __restrict__ out) {
    int i = blockIdx.x * blockDim.x + threadIdx.x;
    if (i < 4 * Hn) out[i] = a[i] + b[i];
}

// GEMM1: (ROWS x 5) @ (5 x 128), no bias (bias comes after aggregation)
__global__ void gemm1_kernel(const float* __restrict__ x, const float* __restrict__ w,
                             float* __restrict__ out) {
    int idx = blockIdx.x * blockDim.x + threadIdx.x;
    if (idx >= ROWS * Hn) return;
    int r = idx >> 7;
    int f = idx & 127;
    const float* xr = x + (size_t)r * Fin;
    float acc = 0.f;
    #pragma unroll
    for (int k = 0; k < Fin; ++k) acc = fmaf(xr[k], w[k * Hn + f], acc);
    out[idx] = acc;
}

// ---------------- GCN aggregation: out[bw][n][f] = relu(sum_e w*ht[bw][col][f] + bias[f])
// block = 128 threads (f), one dst node per block, all 16 bw slices accumulated in registers.
__global__ __launch_bounds__(128) void gcn_agg_kernel(
    const float* __restrict__ ht, const int* __restrict__ row_ptr,
    const int* __restrict__ col, const float* __restrict__ wgt,
    const float* __restrict__ bias, float* __restrict__ out) {
    const int n = blockIdx.x;
    const int f = threadIdx.x;
    const int start = row_ptr[n];
    const int end = row_ptr[n + 1];
    float acc[BWn];
    #pragma unroll
    for (int b = 0; b < BWn; ++b) acc[b] = 0.f;
    for (int e = start; e < end; ++e) {
        const int c = col[e];
        const float w = wgt[e];
        const float* p = ht + (size_t)c * Hn + f;
        #pragma unroll
        for (int b = 0; b < BWn; ++b)
            acc[b] = fmaf(w, p[(size_t)b * Nn * Hn], acc[b]);
    }
    const float bv = bias[f];
    float* q = out + (size_t)n * Hn + f;
    #pragma unroll
    for (int b = 0; b < BWn; ++b)
        q[(size_t)b * Nn * Hn] = fmaxf(acc[b] + bv, 0.f);
}

// ---------------- generic fp32 GEMM ----------------
// C[M x Ncols] = A @ W (+ A2 @ W2) (+ bias), optionally W stored transposed (N x K).
// 64x64 tile, 256 threads, 4x4 microtile, K-chunk 16.
__global__ __launch_bounds__(256) void gemm_kernel(
    const float* __restrict__ A, const float* __restrict__ W,
    const float* __restrict__ A2, const float* __restrict__ W2,
    const float* __restrict__ bias, float* __restrict__ C,
    int M, int Ncols, int K, int transb) {
    __shared__ float As[16][68];
    __shared__ float Bs[16][68];
    const int tid = threadIdx.x;
    const int bm = blockIdx.x * 64;
    const int bn = blockIdx.y * 64;
    const int tm = (tid >> 4) * 4;
    const int tn = (tid & 15) * 4;
    float acc[4][4] = {{0.f}};
    const int npair = (A2 != nullptr) ? 2 : 1;
    for (int pair = 0; pair < npair; ++pair) {
        const float* Ap = pair ? A2 : A;
        const float* Wp = pair ? W2 : W;
        for (int kt = 0; kt < K; kt += 16) {
            {   // A tile: 64 rows x 16 k  (transposed into As[k][m])
                int r = tid >> 2;
                int kk = (tid & 3) << 2;
                int gr = bm + r;
                float4 v = make_float4(0.f, 0.f, 0.f, 0.f);
                if (gr < M) v = *(const float4*)(Ap + (size_t)gr * K + kt + kk);
                As[kk + 0][r] = v.x; As[kk + 1][r] = v.y;
                As[kk + 2][r] = v.z; As[kk + 3][r] = v.w;
            }
            if (!transb) {   // W is K x Ncols
                int k = tid >> 4;
                int nn = (tid & 15) << 2;
                float4 v = *(const float4*)(Wp + (size_t)(kt + k) * Ncols + bn + nn);
                Bs[k][nn + 0] = v.x; Bs[k][nn + 1] = v.y;
                Bs[k][nn + 2] = v.z; Bs[k][nn + 3] = v.w;
            } else {         // W is Ncols x K (row-major), Bs[k][n] = W[n][k]
                int nn = tid >> 2;
                int kk = (tid & 3) << 2;
                float4 v = *(const float4*)(Wp + (size_t)(bn + nn) * K + kt + kk);
                Bs[kk + 0][nn] = v.x; Bs[kk + 1][nn] = v.y;
                Bs[kk + 2][nn] = v.z; Bs[kk + 3][nn] = v.w;
            }
            __syncthreads();
            #pragma unroll
            for (int k = 0; k < 16; ++k) {
                const float4 av = *(const float4*)&As[k][tm];
                const float4 bv = *(const float4*)&Bs[k][tn];
                const float a[4] = {av.x, av.y, av.z, av.w};
                const float bb[4] = {bv.x, bv.y, bv.z, bv.w};
                #pragma unroll
                for (int i = 0; i < 4; ++i)
                    #pragma unroll
                    for (int j = 0; j < 4; ++j)
                        acc[i][j] = fmaf(a[i], bb[j], acc[i][j]);
            }
            __syncthreads();
        }
    }
    float4 bb = make_float4(0.f, 0.f, 0.f, 0.f);
    if (bias) bb = *(const float4*)(bias + bn + tn);
    #pragma unroll
    for (int i = 0; i < 4; ++i) {
        int gr = bm + tm + i;
        if (gr < M) {
            float4 v = make_float4(acc[i][0] + bb.x, acc[i][1] + bb.y,
                                   acc[i][2] + bb.z, acc[i][3] + bb.w);
            *(float4*)(C + (size_t)gr * Ncols + bn + tn) = v;
        }
    }
}

// ---------------- LSTM pointwise ----------------
__global__ void lstm_pointwise_kernel(const float* __restrict__ gates,
                                      float* __restrict__ h, float* __restrict__ c) {
    int idx = blockIdx.x * blockDim.x + threadIdx.x;
    if (idx >= MR * Hn) return;
    int r = idx >> 7;
    int j = idx & 127;
    const float* g = gates + (size_t)r * (4 * Hn);
    float gi = g[j];
    float gf = g[Hn + j];
    float gg = g[2 * Hn + j];
    float go = g[3 * Hn + j];
    float si = 1.f / (1.f + expf(-gi));
    float sf = 1.f / (1.f + expf(-gf));
    float so = 1.f / (1.f + expf(-go));
    float tg = tanhf(gg);
    float cn = sf * c[idx] + si * tg;
    c[idx] = cn;
    h[idx] = so * tanhf(cn);
}

// ---------------- decoder: pred = relu(h @ W1 + b1) @ W2 + b2 ----------------
// one wave per row; lane j computes hidden unit j (64 units), then wave-reduce.
__global__ __launch_bounds__(256) void decoder_kernel(
    const float* __restrict__ h, const float* __restrict__ w1,
    const float* __restrict__ b1, const float* __restrict__ w2,
    const float* __restrict__ b2, float* __restrict__ out) {
    const int wave = threadIdx.x >> 6;
    const int lane = threadIdx.x & 63;
    const int row = blockIdx.x * 4 + wave;
    if (row >= MR) return;
    const float* hr = h + (size_t)row * Hn;
    float d = b1[lane];
    #pragma unroll 8
    for (int k = 0; k < Hn; ++k) d = fmaf(hr[k], w1[k * 64 + lane], d);
    d = fmaxf(d, 0.f);
    float p = d * w2[lane];
    #pragma unroll
    for (int off = 32; off; off >>= 1) p += __shfl_down(p, off);
    if (lane == 0) out[row] = p + b2[0];
}

// ---------------- launch ----------------

extern "C" void kernel_launch(void* const* d_in, const int* in_sizes, int n_in,
                              void* d_out, int out_size, void* d_ws, size_t ws_size,
                              hipStream_t stream) {
    const float* x   = (const float*)d_in[0];
    const int*   ei  = (const int*)d_in[1];
    const float* g1w = (const float*)d_in[2];
    const float* g1b = (const float*)d_in[3];
    const float* g2w = (const float*)d_in[4];
    const float* g2b = (const float*)d_in[5];
    const float* wih = (const float*)d_in[6];
    const float* whh = (const float*)d_in[7];
    const float* bih = (const float*)d_in[8];
    const float* bhh = (const float*)d_in[9];
    const float* dw1 = (const float*)d_in[10];
    const float* db1 = (const float*)d_in[11];
    const float* dw2 = (const float*)d_in[12];
    const float* db2 = (const float*)d_in[13];
    float* out = (float*)d_out;

    // workspace carve (aligned to 256B)
    char* p = (char*)d_ws;
    auto alloc = [&](size_t bytes) {
        char* r = p;
        p += (bytes + 255) & ~(size_t)255;
        return r;
    };
    int*   counts   = (int*)  alloc(Nn * 4);
    int*   row_ptr  = (int*)  alloc((Nn + 1) * 4);
    int*   fill_ptr = (int*)  alloc((Nn + 1) * 4);
    float* dinv     = (float*)alloc(Nn * 4);
    float* bsum     = (float*)alloc(4 * Hn * 4);
    int*   col      = (int*)  alloc((En + Nn) * 4);
    float* wgt      = (float*)alloc((En + Nn) * 4);
    float* bufA     = (float*)alloc((size_t)ROWS * Hn * 4);   // 81.92 MB
    float* bufB     = (float*)alloc((size_t)ROWS * Hn * 4);   // 81.92 MB
    // After agg2, bufA is dead: alias LSTM scratch into it.
    float* gates   = bufA;                                      // 40.96 MB
    float* h_state = (float*)((char*)bufA + 44ull * 1024 * 1024); // 10.24 MB
    float* c_state = (float*)((char*)bufA + 60ull * 1024 * 1024); // 10.24 MB

    // ---- CSR build ----
    init_counts_kernel<<<(Nn + 255) / 256, 256, 0, stream>>>(counts);
    count_edges_kernel<<<(En + 255) / 256, 256, 0, stream>>>(ei, counts);
    scan_kernel<<<1, 1024, 0, stream>>>(counts, row_ptr, fill_ptr, dinv);
    fill_kernel<<<(Nn + En + 255) / 256, 256, 0, stream>>>(ei, dinv, fill_ptr, col, wgt);
    bsum_kernel<<<(4 * Hn + 255) / 256, 256, 0, stream>>>(bih, bhh, bsum);

    // ---- GCN layer 1 ----
    gemm1_kernel<<<(ROWS * Hn + 255) / 256, 256, 0, stream>>>(x, g1w, bufA);
    gcn_agg_kernel<<<Nn, Hn, 0, stream>>>(bufA, row_ptr, col, wgt, g1b, bufB);

    // ---- GCN layer 2 ----
    gemm_kernel<<<dim3(ROWS / 64, Hn / 64), 256, 0, stream>>>(
        bufB, g2w, nullptr, nullptr, nullptr, bufA, ROWS, Hn, Hn, 0);
    gcn_agg_kernel<<<Nn, Hn, 0, stream>>>(bufA, row_ptr, col, wgt, g2b, bufB);
    // bufB now holds h2[bw][n][f]; bufA is dead -> LSTM scratch.

    // ---- LSTM ----
    hipMemsetAsync(h_state, 0, (size_t)MR * Hn * 4, stream);
    hipMemsetAsync(c_state, 0, (size_t)MR * Hn * 4, stream);
    const int mtiles = (Nn + 63) / 64;   // 157
    for (int t = 0; t < Wn; ++t) {
        for (int b = 0; b < Bn; ++b) {
            const float* xt = bufB + (size_t)(b * Wn + t) * Nn * Hn;
            const float* hp = h_state + (size_t)b * Nn * Hn;
            float* gt = gates + (size_t)b * Nn * (4 * Hn);
            gemm_kernel<<<dim3(mtiles, (4 * Hn) / 64), 256, 0, stream>>>(
                xt, wih, hp, whh, bsum, gt, Nn, 4 * Hn, Hn, 1);
        }
        lstm_pointwise_kernel<<<(MR * Hn + 255) / 256, 256, 0, stream>>>(
            gates, h_state, c_state);
    }

    // ---- decoder ----
    decoder_kernel<<<(MR + 3) / 4, 256, 0, stream>>>(h_state, dw1, db1, dw2, db2, out);
}

// Round 2
// 646.992 us; speedup vs baseline: 1.9242x; 1.9242x over previous
//
#include <hip/hip_runtime.h>
#include <hip/hip_fp16.h>
#include <cstdint>
#include <cstddef>

// Problem constants (match reference)
#define Bn   2
#define Wn   8
#define Nn   10000
#define Fin  5
#define En   80000
#define Hn   128
#define BWn  (Bn*Wn)        // 16
#define ROWS (BWn*Nn)       // 160000
#define MR   (Bn*Nn)        // 20000  (LSTM batch rows)

typedef _Float16 half8 __attribute__((ext_vector_type(8)));
typedef float f32x4 __attribute__((ext_vector_type(4)));

// ---------------- CSR build ----------------

__global__ void init_counts_kernel(int* counts) {
    int i = blockIdx.x * blockDim.x + threadIdx.x;
    if (i < Nn) counts[i] = 1;   // self-loop contributes 1 to every dst
}

__global__ void count_edges_kernel(const int* __restrict__ ei, int* counts) {
    int e = blockIdx.x * blockDim.x + threadIdx.x;
    if (e < En) atomicAdd(&counts[ei[En + e]], 1);   // dst row
}

enum { CHUNK = 10 };  // ceil(10000/1024)
static_assert(CHUNK * 1024 >= Nn, "scan chunk");

__global__ __launch_bounds__(1024) void scan_kernel(
    const int* __restrict__ counts, int* __restrict__ row_ptr,
    int* __restrict__ fill_ptr, float* __restrict__ dinv) {
    __shared__ int sums[1024];
    const int t = threadIdx.x;
    const int base = t * CHUNK;
    int cnt[CHUNK];
    int s = 0;
    #pragma unroll
    for (int i = 0; i < CHUNK; ++i) {
        int idx = base + i;
        int v = (idx < Nn) ? counts[idx] : 0;
        cnt[i] = v; s += v;
    }
    sums[t] = s;
    __syncthreads();
    for (int off = 1; off < 1024; off <<= 1) {
        int v = (t >= off) ? sums[t - off] : 0;
        __syncthreads();
        sums[t] += v;
        __syncthreads();
    }
    int excl = (t == 0) ? 0 : sums[t - 1];
    #pragma unroll
    for (int i = 0; i < CHUNK; ++i) {
        int idx = base + i;
        if (idx < Nn) {
            row_ptr[idx] = excl;
            fill_ptr[idx] = excl;
            dinv[idx] = rsqrtf((float)cnt[i]);
            excl += cnt[i];
        }
    }
    if (t == 1023) row_ptr[Nn] = excl;   // = E + N
}

__global__ void fill_kernel(const int* __restrict__ ei,
                            const float* __restrict__ dinv,
                            int* fill_ptr, int* __restrict__ col,
                            float* __restrict__ wgt) {
    int i = blockIdx.x * blockDim.x + threadIdx.x;
    if (i < Nn) {
        // self loop
        int p = atomicAdd(&fill_ptr[i], 1);
        col[p] = i;
        wgt[p] = dinv[i] * dinv[i];
    } else if (i < Nn + En) {
        int e = i - Nn;
        int s = ei[e];
        int d = ei[En + e];
        int p = atomicAdd(&fill_ptr[d], 1);
        col[p] = s;
        wgt[p] = dinv[s] * dinv[d];
    }
}

// ---------------- small helpers ----------------

__global__ void bsum_kernel(const float* __restrict__ a, const float* __restrict__ b,
                            float* __restrict__ out) {
    int i = blockIdx.x * blockDim.x + threadIdx.x;
    if (i < 4 * Hn) out[i] = a[i] + b[i];
}

// fp32 -> f16 weight conversion: wih (512x128), whh (512x128) direct; g2w (128x128) transposed
__global__ void convert_w_kernel(const float* __restrict__ wih, const float* __restrict__ whh,
                                 const float* __restrict__ g2w,
                                 _Float16* __restrict__ wihf, _Float16* __restrict__ whhf,
                                 _Float16* __restrict__ g2wt) {
    int i = blockIdx.x * blockDim.x + threadIdx.x;
    if (i < 65536) {
        wihf[i] = (_Float16)wih[i];
    } else if (i < 131072) {
        whhf[i - 65536] = (_Float16)whh[i - 65536];
    } else if (i < 131072 + 16384) {
        int j = i - 131072;           // output index into g2wt[n][k]
        int n = j >> 7, k = j & 127;
        g2wt[j] = (_Float16)g2w[k * Hn + n];
    }
}

// ---------------- GCN layer 1: aggregate x FIRST (F=5), then transform ----------------
// aggx[bw][n][f] = sum_e w * x[bw][src][f]   (25x less gather than aggregating H=128)
__global__ __launch_bounds__(128) void agg_x_kernel(
    const float* __restrict__ x, const int* __restrict__ row_ptr,
    const int* __restrict__ col, const float* __restrict__ wgt,
    float* __restrict__ aggx) {
    const int n = blockIdx.x;
    const int t = threadIdx.x;
    const int s = t >> 3, f = t & 7;
    if (f >= Fin) return;
    const int start = row_ptr[n], end = row_ptr[n + 1];
    float acc = 0.f;
    for (int e = start; e < end; ++e) {
        int c = col[e];
        acc = fmaf(wgt[e], x[((size_t)s * Nn + c) * Fin + f], acc);
    }
    aggx[((size_t)s * Nn + n) * Fin + f] = acc;
}

// h1[row][j] = relu(aggx[row][:] @ W1[:,j] + b1[j]), output f16
__global__ void gemm1f_kernel(const float* __restrict__ aggx, const float* __restrict__ w,
                              const float* __restrict__ bias, _Float16* __restrict__ out) {
    int idx = blockIdx.x * blockDim.x + threadIdx.x;
    if (idx >= ROWS * Hn) return;
    int row = idx >> 7, j = idx & 127;
    const float* ar = aggx + (size_t)row * Fin;
    float s = bias[j];
    #pragma unroll
    for (int f = 0; f < Fin; ++f) s = fmaf(ar[f], w[f * Hn + j], s);
    out[idx] = (_Float16)fmaxf(s, 0.f);
}

// ---------------- GCN layer 2 aggregation: f16 in, f16 out, fp32 accumulate ----------------
// out[(s*Nn+n)*H + f] = relu(sum_e w*ht[(s*Nn+c)*H+f] + bias[f])
__global__ __launch_bounds__(128) void gcn_agg2_kernel(
    const _Float16* __restrict__ ht, const int* __restrict__ row_ptr,
    const int* __restrict__ col, const float* __restrict__ wgt,
    const float* __restrict__ bias, _Float16* __restrict__ out) {
    const int n = blockIdx.x;
    const int f = threadIdx.x;
    const int start = row_ptr[n], end = row_ptr[n + 1];
    float acc[BWn];
    #pragma unroll
    for (int s = 0; s < BWn; ++s) acc[s] = 0.f;
    for (int e = start; e < end; ++e) {
        const int c = col[e];
        const float w = wgt[e];
        const _Float16* p = ht + (size_t)c * Hn + f;
        #pragma unroll
        for (int s = 0; s < BWn; ++s)
            acc[s] = fmaf(w, (float)p[(size_t)s * Nn * Hn], acc[s]);
    }
    const float bv = bias[f];
    #pragma unroll
    for (int s = 0; s < BWn; ++s)
        out[((size_t)s * Nn + n) * Hn + f] = (_Float16)fmaxf(acc[s] + bv, 0.f);
}

// ---------------- f16 MFMA GEMM ----------------
// C[M x Nc] (f16) = A1 @ B1^T (+ A2 @ B2^T) (+ bias), K=128 per pass.
// B matrices stored [n][k] row-major (torch weight layout) -> exactly MFMA B-operand order.
// step >= 0: pass-0 A rows are remapped LSTM x-slices: gr -> ((b*8+step)*10000 + n).
// Tiles: BM=128, BN=128, BK=32; 4 waves, each 64x64 via 4x4 grid of 16x16x32 MFMAs.
__global__ __launch_bounds__(256) void gemm_f16_kernel(
    const _Float16* __restrict__ A1, const _Float16* __restrict__ A2,
    const _Float16* __restrict__ B1, const _Float16* __restrict__ B2,
    const float* __restrict__ bias, _Float16* __restrict__ C,
    int M, int Nc, int step) {
    __shared__ _Float16 As[128][40];   // pitch 40 f16 = 80 B (16B-aligned, conflict-benign)
    __shared__ _Float16 Bs[128][40];
    const int tid = threadIdx.x;
    const int m0 = blockIdx.x * 128;
    const int n0 = blockIdx.y * 128;
    const int wave = tid >> 6;
    const int lane = tid & 63;
    const int l = lane & 15, q = lane >> 4;
    const int wm = (wave & 1) * 64, wn = (wave >> 1) * 64;
    f32x4 acc[4][4];
    #pragma unroll
    for (int i = 0; i < 4; ++i)
        #pragma unroll
        for (int j = 0; j < 4; ++j)
            acc[i][j] = (f32x4){0.f, 0.f, 0.f, 0.f};

    const int npass = (A2 != nullptr) ? 2 : 1;
    for (int pass = 0; pass < npass; ++pass) {
        const _Float16* Ap = pass ? A2 : A1;
        const _Float16* Bp = pass ? B2 : B1;
        for (int kt = 0; kt < 128; kt += 32) {
            // stage: 128 rows x 32 k, 8-f16 chunks; 512 chunks over 256 threads x 2
            #pragma unroll
            for (int j = 0; j < 2; ++j) {
                int idx = tid + j * 256;
                int r = idx >> 2, c = (idx & 3) * 8;
                int gr = m0 + r;
                half8 v = {0, 0, 0, 0, 0, 0, 0, 0};
                if (gr < M) {
                    size_t arow = (size_t)gr;
                    if (pass == 0 && step >= 0) {
                        int b = (gr >= Nn) ? 1 : 0;
                        arow = (size_t)(b * Wn + step) * Nn + (gr - b * Nn);
                    }
                    v = *(const half8*)(Ap + arow * 128 + kt + c);
                }
                *(half8*)&As[r][c] = v;
                int nr = n0 + r;   // Nc is a multiple of 128 -> no guard
                *(half8*)&Bs[r][c] = *(const half8*)(Bp + (size_t)nr * 128 + kt + c);
            }
            __syncthreads();
            half8 af[4], bf[4];
            #pragma unroll
            for (int i = 0; i < 4; ++i) af[i] = *(const half8*)&As[wm + i * 16 + l][q * 8];
            #pragma unroll
            for (int j = 0; j < 4; ++j) bf[j] = *(const half8*)&Bs[wn + j * 16 + l][q * 8];
            #pragma unroll
            for (int i = 0; i < 4; ++i)
                #pragma unroll
                for (int j = 0; j < 4; ++j)
                    acc[i][j] = __builtin_amdgcn_mfma_f32_16x16x32_f16(
                        af[i], bf[j], acc[i][j], 0, 0, 0);
            __syncthreads();
        }
    }
    // epilogue: C/D layout col=lane&15, row=(lane>>4)*4+reg
    #pragma unroll
    for (int j = 0; j < 4; ++j) {
        int gcol = n0 + wn + j * 16 + l;
        float bv = bias ? bias[gcol] : 0.f;
        #pragma unroll
        for (int i = 0; i < 4; ++i) {
            #pragma unroll
            for (int r = 0; r < 4; ++r) {
                int grow = m0 + wm + i * 16 + q * 4 + r;
                if (grow < M)
                    C[(size_t)grow * Nc + gcol] = (_Float16)(acc[i][j][r] + bv);
            }
        }
    }
}

// ---------------- LSTM pointwise ----------------
__global__ void lstm_pointwise_kernel(const _Float16* __restrict__ gates,
                                      _Float16* __restrict__ h, float* __restrict__ c) {
    int idx = blockIdx.x * blockDim.x + threadIdx.x;
    if (idx >= MR * Hn) return;
    int r = idx >> 7;
    int j = idx & 127;
    const _Float16* g = gates + (size_t)r * (4 * Hn);
    float gi = (float)g[j];
    float gf = (float)g[Hn + j];
    float gg = (float)g[2 * Hn + j];
    float go = (float)g[3 * Hn + j];
    float si = 1.f / (1.f + expf(-gi));
    float sf = 1.f / (1.f + expf(-gf));
    float so = 1.f / (1.f + expf(-go));
    float tg = tanhf(gg);
    float cn = sf * c[idx] + si * tg;
    c[idx] = cn;
    h[idx] = (_Float16)(so * tanhf(cn));
}

// ---------------- decoder: pred = relu(h @ W1 + b1) @ W2 + b2 ----------------
__global__ __launch_bounds__(256) void decoder_kernel(
    const _Float16* __restrict__ h, const float* __restrict__ w1,
    const float* __restrict__ b1, const float* __restrict__ w2,
    const float* __restrict__ b2, float* __restrict__ out) {
    const int wave = threadIdx.x >> 6;
    const int lane = threadIdx.x & 63;
    const int row = blockIdx.x * 4 + wave;
    if (row >= MR) return;
    const _Float16* hr = h + (size_t)row * Hn;
    float d = b1[lane];
    #pragma unroll 8
    for (int k = 0; k < Hn; ++k) d = fmaf((float)hr[k], w1[k * 64 + lane], d);
    d = fmaxf(d, 0.f);
    float p = d * w2[lane];
    #pragma unroll
    for (int off = 32; off; off >>= 1) p += __shfl_down(p, off);
    if (lane == 0) out[row] = p + b2[0];
}

// ---------------- launch ----------------

extern "C" void kernel_launch(void* const* d_in, const int* in_sizes, int n_in,
                              void* d_out, int out_size, void* d_ws, size_t ws_size,
                              hipStream_t stream) {
    const float* x   = (const float*)d_in[0];
    const int*   ei  = (const int*)d_in[1];
    const float* g1w = (const float*)d_in[2];
    const float* g1b = (const float*)d_in[3];
    const float* g2w = (const float*)d_in[4];
    const float* g2b = (const float*)d_in[5];
    const float* wih = (const float*)d_in[6];
    const float* whh = (const float*)d_in[7];
    const float* bih = (const float*)d_in[8];
    const float* bhh = (const float*)d_in[9];
    const float* dw1 = (const float*)d_in[10];
    const float* db1 = (const float*)d_in[11];
    const float* dw2 = (const float*)d_in[12];
    const float* db2 = (const float*)d_in[13];
    float* out = (float*)d_out;

    // workspace carve (256B aligned)
    char* p = (char*)d_ws;
    auto alloc = [&](size_t bytes) {
        char* r = p;
        p += (bytes + 255) & ~(size_t)255;
        return r;
    };
    int*      counts   = (int*)     alloc(Nn * 4);
    int*      row_ptr  = (int*)     alloc((Nn + 1) * 4);
    int*      fill_ptr = (int*)     alloc((Nn + 1) * 4);
    float*    dinv     = (float*)   alloc(Nn * 4);
    float*    bsum     = (float*)   alloc(4 * Hn * 4);
    int*      col      = (int*)     alloc((En + Nn) * 4);
    float*    wgt      = (float*)   alloc((En + Nn) * 4);
    _Float16* wihf     = (_Float16*)alloc(512 * 128 * 2);
    _Float16* whhf     = (_Float16*)alloc(512 * 128 * 2);
    _Float16* g2wt     = (_Float16*)alloc(128 * 128 * 2);
    float*    aggx     = (float*)   alloc((size_t)ROWS * Fin * 4);    // 3.2 MB
    _Float16* h1f      = (_Float16*)alloc((size_t)ROWS * Hn * 2);     // 41 MB
    _Float16* htf      = (_Float16*)alloc((size_t)ROWS * Hn * 2);     // 41 MB
    _Float16* h2f      = (_Float16*)alloc((size_t)ROWS * Hn * 2);     // 41 MB
    _Float16* gates    = (_Float16*)alloc((size_t)MR * 4 * Hn * 2);   // 20.5 MB
    _Float16* hf       = (_Float16*)alloc((size_t)MR * Hn * 2);       // 5.1 MB
    float*    c_state  = (float*)   alloc((size_t)MR * Hn * 4);       // 10.2 MB

    // ---- CSR build + weight prep ----
    init_counts_kernel<<<(Nn + 255) / 256, 256, 0, stream>>>(counts);
    count_edges_kernel<<<(En + 255) / 256, 256, 0, stream>>>(ei, counts);
    scan_kernel<<<1, 1024, 0, stream>>>(counts, row_ptr, fill_ptr, dinv);
    fill_kernel<<<(Nn + En + 255) / 256, 256, 0, stream>>>(ei, dinv, fill_ptr, col, wgt);
    bsum_kernel<<<(4 * Hn + 255) / 256, 256, 0, stream>>>(bih, bhh, bsum);
    convert_w_kernel<<<(131072 + 16384 + 255) / 256, 256, 0, stream>>>(
        wih, whh, g2w, wihf, whhf, g2wt);

    // ---- GCN layer 1: aggregate (F=5) then transform ----
    agg_x_kernel<<<Nn, 128, 0, stream>>>(x, row_ptr, col, wgt, aggx);
    gemm1f_kernel<<<(ROWS * Hn + 255) / 256, 256, 0, stream>>>(aggx, g1w, g1b, h1f);

    // ---- GCN layer 2: transform (MFMA) then aggregate ----
    gemm_f16_kernel<<<dim3(ROWS / 128, 1), 256, 0, stream>>>(
        h1f, nullptr, g2wt, nullptr, nullptr, htf, ROWS, Hn, -1);
    gcn_agg2_kernel<<<Nn, Hn, 0, stream>>>(htf, row_ptr, col, wgt, g2b, h2f);

    // ---- LSTM ----
    hipMemsetAsync(hf, 0, (size_t)MR * Hn * 2, stream);
    hipMemsetAsync(c_state, 0, (size_t)MR * Hn * 4, stream);
    const int mtiles = (MR + 127) / 128;   // 157
    for (int t = 0; t < Wn; ++t) {
        gemm_f16_kernel<<<dim3(mtiles, 4), 256, 0, stream>>>(
            h2f, hf, wihf, whhf, bsum, gates, MR, 4 * Hn, t);
        lstm_pointwise_kernel<<<(MR * Hn + 255) / 256, 256, 0, stream>>>(
            gates, hf, c_state);
    }

    // ---- decoder ----
    decoder_kernel<<<(MR + 3) / 4, 256, 0, stream>>>(hf, dw1, db1, dw2, db2, out);
}